// Round 4
// baseline (290.124 us; speedup 1.0000x reference)
//
#include <hip/hip_runtime.h>

// Output layout (f32 elements), concatenated in reference return order:
//   w_dist  (128,256,1024) @ 0          (also split-K partial scratch)
//   idx     (128,256,1)    @ 33554432   (written as float)
//   w_recon (128,4096)     @ 33587200
//   mu      (128,512)      @ 34111488
//   log_var (128,512)      @ 34177024
#define OFF_WDIST 0
#define OFF_IDX   33554432
#define OFF_WREC  33587200
#define OFF_MU    34111488
#define OFF_LV    34177024

// ---------------------------------------------------------------------------
// Encoder GEMM stage 1 (split-K partials, W streamed from global).
// h[b][j] = sum_i x[b][i]*W_enc[i][j];  x[b][e*256+dc] = w_q[b][dc*16+e].
// K-chunk kc covers w_q cols [kc*64, kc*64+64): dc in [kc*4,kc*4+4), e in [0,16)
//   W row gi(e,d) = e*256 + kc*4 + d ; xs_t row l = d*16 + e
// grid = 1024: jt (16 tiles of 64 cols) x kc (64 chunks of 64 K). block 256.
// thread tile 8x4. LDS = 32 KB (x only; W global, read exactly once).
// ---------------------------------------------------------------------------
__global__ __launch_bounds__(256) void enc_gemm1_kernel(const float* __restrict__ w_q,
                                                        const float* __restrict__ W_enc,
                                                        float* __restrict__ part) {
    __shared__ float xs_t[64 * 128];  // [l][b]
    const int tid = threadIdx.x;
    const int jt = blockIdx.x & 15;   // 16 col tiles of 64
    const int kc = blockIdx.x >> 4;   // 64 K-chunks of 64

    // stage xs_t: 4 lanes cover one full 64-float row (256B line-perfect)
    {
        const int b0 = tid >> 2;
        const int q = tid & 3;
#pragma unroll
        for (int pass = 0; pass < 2; ++pass) {
            const int b = pass * 64 + b0;
            const float* src = w_q + b * 4096 + kc * 64 + q * 16;
#pragma unroll
            for (int u = 0; u < 4; ++u) {
                const float4 v = *(const float4*)(src + u * 4);
                const int l0 = q * 16 + u * 4;
                xs_t[(l0 + 0) * 128 + b] = v.x;
                xs_t[(l0 + 1) * 128 + b] = v.y;
                xs_t[(l0 + 2) * 128 + b] = v.z;
                xs_t[(l0 + 3) * 128 + b] = v.w;
            }
        }
    }
    __syncthreads();

    const int tx = tid & 15;   // 4 cols at jt*64 + tx*4
    const int ty = tid >> 4;   // 8 rows at ty*8
    const float* wp = W_enc + (size_t)(kc * 4) * 1024 + jt * 64 + tx * 4;

    float acc[8][4];
#pragma unroll
    for (int r = 0; r < 8; ++r)
#pragma unroll
        for (int c = 0; c < 4; ++c) acc[r][c] = 0.f;

#pragma unroll 2
    for (int e = 0; e < 16; ++e) {
#pragma unroll
        for (int d = 0; d < 4; ++d) {
            const float4 w = *(const float4*)(wp + (size_t)(e * 256 + d) * 1024);
            const int l = d * 16 + e;
            const float4 a0 = *(const float4*)&xs_t[l * 128 + ty * 8];
            const float4 a1 = *(const float4*)&xs_t[l * 128 + ty * 8 + 4];
            const float av[8] = {a0.x, a0.y, a0.z, a0.w, a1.x, a1.y, a1.z, a1.w};
#pragma unroll
            for (int r = 0; r < 8; ++r) {
                acc[r][0] = fmaf(av[r], w.x, acc[r][0]);
                acc[r][1] = fmaf(av[r], w.y, acc[r][1]);
                acc[r][2] = fmaf(av[r], w.z, acc[r][2]);
                acc[r][3] = fmaf(av[r], w.w, acc[r][3]);
            }
        }
    }

    // part[(kc*128 + b)*1024 + jt*64 + col]
#pragma unroll
    for (int r = 0; r < 8; ++r) {
        const int brow = ty * 8 + r;
        float* dst = part + (size_t)(kc * 128 + brow) * 1024 + jt * 64 + tx * 4;
        *(float4*)dst = make_float4(acc[r][0], acc[r][1], acc[r][2], acc[r][3]);
    }
}

// ---------------------------------------------------------------------------
// Encoder reduce: mu/log_var = b_enc + sum over 64 partials. grid 512x256.
// ---------------------------------------------------------------------------
__global__ __launch_bounds__(256) void enc_reduce_kernel(const float* __restrict__ part,
                                                         const float* __restrict__ b_enc,
                                                         float* __restrict__ mu_out,
                                                         float* __restrict__ lv_out) {
    const int g = blockIdx.x * 256 + threadIdx.x;
    const int b = g >> 10;
    const int j = g & 1023;
    float sum = b_enc[j];
#pragma unroll 8
    for (int kc = 0; kc < 64; ++kc) {
        sum += part[(size_t)((kc * 128 + b) << 10) + j];
    }
    if (j < 512) mu_out[b * 512 + j] = sum;
    else         lv_out[b * 512 + (j - 512)] = sum;
}

// ---------------------------------------------------------------------------
// Decoder GEMM stage 1: w_recon partials = mu @ W_dec (M=128,K=512,N=4096)
// grid = 1024: ct (64 tiles of 64 cols) x kc (16 chunks of 32 K). block 256.
// thread tile 8x4. LDS 16 KB (x only; W_dec streamed, read exactly once).
// ---------------------------------------------------------------------------
__global__ __launch_bounds__(256) void dec_gemm1_kernel(const float* __restrict__ mu_in,
                                                        const float* __restrict__ W_dec,
                                                        float* __restrict__ part) {
    __shared__ float xs_t[32 * 128];  // [l][b]
    const int tid = threadIdx.x;
    const int ct = blockIdx.x & 63;   // 64 col tiles of 64
    const int kc = blockIdx.x >> 6;   // 16 K-chunks of 32

    {
        const int b = tid >> 1;       // 128 rows, 2 lanes per row (64B line)
        const int q = tid & 1;
        const float* src = mu_in + b * 512 + kc * 32 + q * 16;
#pragma unroll
        for (int u = 0; u < 4; ++u) {
            const float4 v = *(const float4*)(src + u * 4);
            const int l0 = q * 16 + u * 4;
            xs_t[(l0 + 0) * 128 + b] = v.x;
            xs_t[(l0 + 1) * 128 + b] = v.y;
            xs_t[(l0 + 2) * 128 + b] = v.z;
            xs_t[(l0 + 3) * 128 + b] = v.w;
        }
    }
    __syncthreads();

    const int tx = tid & 15;
    const int ty = tid >> 4;
    const float* wp = W_dec + (size_t)(kc * 32) * 4096 + ct * 64 + tx * 4;

    float acc[8][4];
#pragma unroll
    for (int r = 0; r < 8; ++r)
#pragma unroll
        for (int c = 0; c < 4; ++c) acc[r][c] = 0.f;

#pragma unroll 8
    for (int l = 0; l < 32; ++l) {
        const float4 w = *(const float4*)(wp + (size_t)l * 4096);
        const float4 a0 = *(const float4*)&xs_t[l * 128 + ty * 8];
        const float4 a1 = *(const float4*)&xs_t[l * 128 + ty * 8 + 4];
        const float av[8] = {a0.x, a0.y, a0.z, a0.w, a1.x, a1.y, a1.z, a1.w};
#pragma unroll
        for (int r = 0; r < 8; ++r) {
            acc[r][0] = fmaf(av[r], w.x, acc[r][0]);
            acc[r][1] = fmaf(av[r], w.y, acc[r][1]);
            acc[r][2] = fmaf(av[r], w.z, acc[r][2]);
            acc[r][3] = fmaf(av[r], w.w, acc[r][3]);
        }
    }

#pragma unroll
    for (int r = 0; r < 8; ++r) {
        const int brow = ty * 8 + r;
        float* dst = part + (size_t)(kc * 128 + brow) * 4096 + ct * 64 + tx * 4;
        *(float4*)dst = make_float4(acc[r][0], acc[r][1], acc[r][2], acc[r][3]);
    }
}

// ---------------------------------------------------------------------------
// Decoder reduce: w_recon = b_dec + sum over 16 partials. grid 2048x256.
// ---------------------------------------------------------------------------
__global__ __launch_bounds__(256) void dec_reduce_kernel(const float* __restrict__ part,
                                                         const float* __restrict__ b_dec,
                                                         float* __restrict__ wrec_out) {
    const int g = blockIdx.x * 256 + threadIdx.x;
    const int b = g >> 12;
    const int n = g & 4095;
    float sum = b_dec[n];
#pragma unroll
    for (int kc = 0; kc < 16; ++kc) {
        sum += part[(size_t)((kc * 128 + b) << 12) + n];
    }
    wrec_out[b * 4096 + n] = sum;
}

// ---------------------------------------------------------------------------
// Distances + argmin (low-VGPR, LDS-broadcast rows).
// grid = 4096: dc (256) x bg (16 groups of 8 rows). block 256.
// lane t handles k = kk*256 + t (kk=0..3): contiguous codebook loads (4KB/wave)
// and contiguous 1KB stores per (kk,row). wrec rows live in LDS (512B),
// read via wave-uniform broadcast. ~60 VGPR -> high occupancy.
// ---------------------------------------------------------------------------
__global__ __launch_bounds__(256) void dist_kernel(const float* __restrict__ wrec,
                                                   const float* __restrict__ cbk,
                                                   float* __restrict__ wdist,
                                                   float* __restrict__ idx_out) {
    const int dc = blockIdx.x & 255;
    const int bg = blockIdx.x >> 8;
    const int t = threadIdx.x;

    __shared__ float xs[8][16];
    __shared__ float x2s[8];

    if (t < 32) {
        const int r = t >> 2, q = t & 3;
        *(float4*)&xs[r][q * 4] =
            *(const float4*)(wrec + (size_t)(bg * 8 + r) * 4096 + dc * 16 + q * 4);
    }
    __syncthreads();
    if (t < 8) {
        float s = 0.f;
#pragma unroll
        for (int i = 0; i < 16; ++i) s = fmaf(xs[t][i], xs[t][i], s);
        x2s[t] = s;
    }
    __syncthreads();

    const float* cbp = cbk + (size_t)dc * 16384;
    float minv[8];
    int mink[8];
#pragma unroll
    for (int r = 0; r < 8; ++r) { minv[r] = 3.4e38f; mink[r] = 0; }

    for (int kk = 0; kk < 4; ++kk) {
        const int k = kk * 256 + t;
        const float4* cp = (const float4*)(cbp + (size_t)k * 16);
        const float4 c0 = cp[0], c1 = cp[1], c2 = cp[2], c3 = cp[3];
        float cc = 0.f;
        cc = fmaf(c0.x, c0.x, cc); cc = fmaf(c0.y, c0.y, cc);
        cc = fmaf(c0.z, c0.z, cc); cc = fmaf(c0.w, c0.w, cc);
        cc = fmaf(c1.x, c1.x, cc); cc = fmaf(c1.y, c1.y, cc);
        cc = fmaf(c1.z, c1.z, cc); cc = fmaf(c1.w, c1.w, cc);
        cc = fmaf(c2.x, c2.x, cc); cc = fmaf(c2.y, c2.y, cc);
        cc = fmaf(c2.z, c2.z, cc); cc = fmaf(c2.w, c2.w, cc);
        cc = fmaf(c3.x, c3.x, cc); cc = fmaf(c3.y, c3.y, cc);
        cc = fmaf(c3.z, c3.z, cc); cc = fmaf(c3.w, c3.w, cc);

        float* obase = wdist + (size_t)((bg * 8) * 256 + dc) * 1024 + k;
#pragma unroll
        for (int r = 0; r < 8; ++r) {
            const float4 x0 = *(const float4*)&xs[r][0];
            const float4 x1 = *(const float4*)&xs[r][4];
            const float4 x2v = *(const float4*)&xs[r][8];
            const float4 x3 = *(const float4*)&xs[r][12];
            float cr = 0.f;
            cr = fmaf(x0.x, c0.x, cr); cr = fmaf(x0.y, c0.y, cr);
            cr = fmaf(x0.z, c0.z, cr); cr = fmaf(x0.w, c0.w, cr);
            cr = fmaf(x1.x, c1.x, cr); cr = fmaf(x1.y, c1.y, cr);
            cr = fmaf(x1.z, c1.z, cr); cr = fmaf(x1.w, c1.w, cr);
            cr = fmaf(x2v.x, c2.x, cr); cr = fmaf(x2v.y, c2.y, cr);
            cr = fmaf(x2v.z, c2.z, cr); cr = fmaf(x2v.w, c2.w, cr);
            cr = fmaf(x3.x, c3.x, cr); cr = fmaf(x3.y, c3.y, cr);
            cr = fmaf(x3.z, c3.z, cr); cr = fmaf(x3.w, c3.w, cr);
            const float dd = (x2s[r] + cc) - 2.f * cr;
            obase[(size_t)r * 262144] = dd;
            if (dd < minv[r]) { minv[r] = dd; mink[r] = k; }
        }
    }

    __shared__ float rvs[8][4];
    __shared__ int rks[8][4];
    const int lane = t & 63;
    const int wv = t >> 6;
#pragma unroll
    for (int r = 0; r < 8; ++r) {
        float v = minv[r];
        int k = mink[r];
#pragma unroll
        for (int off = 32; off > 0; off >>= 1) {
            float ov = __shfl_down(v, off);
            int ok = __shfl_down(k, off);
            if (ov < v || (ov == v && ok < k)) { v = ov; k = ok; }
        }
        if (lane == 0) { rvs[r][wv] = v; rks[r][wv] = k; }
    }
    __syncthreads();
    if (t < 8) {
        float v = rvs[t][0];
        int k = rks[t][0];
#pragma unroll
        for (int w = 1; w < 4; ++w) {
            float ov = rvs[t][w];
            int ok = rks[t][w];
            if (ov < v || (ov == v && ok < k)) { v = ov; k = ok; }
        }
        idx_out[(bg * 8 + t) * 256 + dc] = (float)k;
    }
}

extern "C" void kernel_launch(void* const* d_in, const int* in_sizes, int n_in,
                              void* d_out, int out_size, void* d_ws, size_t ws_size,
                              hipStream_t stream) {
    const float* w_q   = (const float*)d_in[0];
    // d_in[1] = pseudo_inputs: unused (pseudo rows of h are discarded)
    const float* W_enc = (const float*)d_in[2];
    const float* b_enc = (const float*)d_in[3];
    const float* W_dec = (const float*)d_in[4];
    const float* b_dec = (const float*)d_in[5];
    const float* cbk   = (const float*)d_in[6];
    float* out = (float*)d_out;

    float* mu_out = out + OFF_MU;
    float* lv_out = out + OFF_LV;
    float* wrec   = out + OFF_WREC;
    float* wdist  = out + OFF_WDIST;
    float* idx_o  = out + OFF_IDX;
    float* part   = out + OFF_WDIST;  // 32 MB scratch, consumed before dist

    hipLaunchKernelGGL(enc_gemm1_kernel,  dim3(1024), dim3(256), 0, stream, w_q, W_enc, part);
    hipLaunchKernelGGL(enc_reduce_kernel, dim3(512),  dim3(256), 0, stream, part, b_enc, mu_out, lv_out);
    hipLaunchKernelGGL(dec_gemm1_kernel,  dim3(1024), dim3(256), 0, stream, mu_out, W_dec, part);
    hipLaunchKernelGGL(dec_reduce_kernel, dim3(2048), dim3(256), 0, stream, part, b_dec, wrec);
    hipLaunchKernelGGL(dist_kernel,       dim3(4096), dim3(256), 0, stream, wrec, cbk, wdist, idx_o);
}